// Round 7
// baseline (297.402 us; speedup 1.0000x reference)
//
#include <hip/hip_runtime.h>

#define B_ 2
#define N_ 2048
#define D_ 1024
#define H_ 16
#define DH_ 64

typedef _Float16 half8 __attribute__((ext_vector_type(8)));
typedef _Float16 half4 __attribute__((ext_vector_type(4)));
typedef float f32x4 __attribute__((ext_vector_type(4)));

__device__ __forceinline__ void gl2lds16(const _Float16* g, _Float16* l) {
  __builtin_amdgcn_global_load_lds(
      (const __attribute__((address_space(1))) void*)g,
      (__attribute__((address_space(3))) void*)l, 16, 0, 0);
}

// ---------------------------------------------------------------------------
// Fused prep: [0,6144) convert q/k/v fp32->fp16; [6144,7168) convert+transpose
// weights to fp16 W^T; [7168] rank heads by valid_len desc (LPT order).
__global__ __launch_bounds__(256) void prep_kernel(
    const float* __restrict__ q, const float* __restrict__ k,
    const float* __restrict__ v, const float* __restrict__ Wq,
    const float* __restrict__ Wk, const float* __restrict__ Wv,
    const float* __restrict__ Wo, const int* __restrict__ vlen,
    _Float16* __restrict__ Xf, _Float16* __restrict__ WtAll,
    int* __restrict__ order) {
  __shared__ float tile[64][65];
  const int bid = blockIdx.x;
  if (bid < 6144) {
    int y = bid >> 11, x = bid & 2047;
    const float* s = (y == 0) ? q : (y == 1) ? k : v;
    _Float16* d = Xf + (size_t)y * ((size_t)B_ * N_ * D_);
    size_t idx = ((size_t)x * 256 + threadIdx.x) * 8;
    float4 a = *(const float4*)(s + idx);
    float4 b = *(const float4*)(s + idx + 4);
    half8 h;
    h[0] = (_Float16)a.x; h[1] = (_Float16)a.y; h[2] = (_Float16)a.z; h[3] = (_Float16)a.w;
    h[4] = (_Float16)b.x; h[5] = (_Float16)b.y; h[6] = (_Float16)b.z; h[7] = (_Float16)b.w;
    *(half8*)(d + idx) = h;
  } else if (bid < 6144 + 1024) {
    int idx = bid - 6144;
    int z = idx >> 8, rem = idx & 255, gy = rem >> 4, gx = rem & 15;
    const float* W = (z == 0) ? Wq : (z == 1) ? Wk : (z == 2) ? Wv : Wo;
    _Float16* Wt = WtAll + (size_t)z * D_ * D_;
    int k0 = gy * 64, n0 = gx * 64;
    int tr = threadIdx.x >> 4, tc = threadIdx.x & 15;
#pragma unroll
    for (int i = 0; i < 4; ++i) {
      int r = tr + i * 16;
      float4 va = *(const float4*)(W + (size_t)(k0 + r) * D_ + n0 + tc * 4);
      tile[r][tc * 4 + 0] = va.x; tile[r][tc * 4 + 1] = va.y;
      tile[r][tc * 4 + 2] = va.z; tile[r][tc * 4 + 3] = va.w;
    }
    __syncthreads();
#pragma unroll
    for (int i = 0; i < 4; ++i) {
      int r = tr + i * 16;
      half4 hv;
      hv[0] = (_Float16)tile[tc * 4 + 0][r];
      hv[1] = (_Float16)tile[tc * 4 + 1][r];
      hv[2] = (_Float16)tile[tc * 4 + 2][r];
      hv[3] = (_Float16)tile[tc * 4 + 3][r];
      *(half4*)(Wt + (size_t)(n0 + r) * D_ + k0 + tc * 4) = hv;
    }
  } else {
    int i = threadIdx.x;
    if (i < B_ * H_) {
      int vi = vlen[i], rank = 0;
      for (int j = 0; j < B_ * H_; ++j) {
        int vj = vlen[j];
        if (vj > vi || (vj == vi && j < i)) ++rank;
      }
      order[rank] = i;
    }
  }
}

// ---------------------------------------------------------------------------
// fp16 MFMA GEMM (R2-proven structure): BK=32, single-buffer, 16 MFMA/barrier.
// MODE 0: z=0/1 -> fp16 head-split (B,H,N,DH); z=2 -> fp16 transposed-V
//         VtG[bh][dh][key] (contiguous half4 stores).  MODE 1: fp32 row-major.
#define BK 32

template <int NT, int MODE>
__global__ __launch_bounds__(256) void gemm_f16_kernel(
    const _Float16* __restrict__ Aall, const _Float16* __restrict__ Btall,
    _Float16* __restrict__ ChAll, _Float16* __restrict__ VtG,
    float* __restrict__ Cf32) {
  constexpr int BN = NT * 32;
  constexpr int K = D_;
  __shared__ __attribute__((aligned(16))) _Float16 As[128 * BK];
  __shared__ __attribute__((aligned(16))) _Float16 Bs[BN * BK];
  const int z = blockIdx.z;
  const _Float16* A  = Aall  + (size_t)z * ((size_t)B_ * N_ * D_);
  const _Float16* Bt = Btall + (size_t)z * ((size_t)D_ * D_);
  _Float16* Chead = ChAll + (size_t)z * ((size_t)B_ * N_ * D_);

  const int tid = threadIdx.x;
  const int m0 = blockIdx.y * 128, n0 = blockIdx.x * BN;
  const int lane = tid & 63, w = tid >> 6;
  const int quad = lane >> 4, l15 = lane & 15;
  const int wm = (w >> 1) * 64, wn = (w & 1) * (BN / 2);
  const int swz = (quad ^ ((l15 >> 1) & 3)) * 8;
  f32x4 acc[4][NT] = {};

  for (int kt = 0; kt < K; kt += BK) {
    if (kt) __syncthreads();
#pragma unroll
    for (int p = 0; p < 2; ++p) {
      int c = p * 256 + tid;
      int row = c >> 2, pg = c & 3;
      int gl = pg ^ ((row >> 1) & 3);
      gl2lds16(A + (size_t)(m0 + row) * K + kt + gl * 8, &As[c * 8]);
    }
#pragma unroll
    for (int p = 0; p < NT / 2; ++p) {
      int c = p * 256 + tid;
      int row = c >> 2, pg = c & 3;
      int gl = pg ^ ((row >> 1) & 3);
      gl2lds16(Bt + (size_t)(n0 + row) * K + kt + gl * 8, &Bs[c * 8]);
    }
    __syncthreads();
    half8 af[4], bf[NT];
#pragma unroll
    for (int mt = 0; mt < 4; ++mt)
      af[mt] = *(const half8*)&As[(wm + mt * 16 + l15) * 32 + swz];
#pragma unroll
    for (int nt = 0; nt < NT; ++nt)
      bf[nt] = *(const half8*)&Bs[(wn + nt * 16 + l15) * 32 + swz];
#pragma unroll
    for (int mt = 0; mt < 4; ++mt)
#pragma unroll
      for (int nt = 0; nt < NT; ++nt)
        acc[mt][nt] = __builtin_amdgcn_mfma_f32_16x16x32_f16(
            af[mt], bf[nt], acc[mt][nt], 0, 0, 0);
  }

#pragma unroll
  for (int mt = 0; mt < 4; ++mt) {
    int mrow = m0 + wm + mt * 16 + quad * 4;
#pragma unroll
    for (int nt = 0; nt < NT; ++nt) {
      int jcol = n0 + wn + nt * 16 + l15;
      if (MODE == 0 && z == 2) {
        // transposed V: VtG[(bh*DH + dh)*N + key], 4 consecutive keys
        int b = mrow >> 11, key = mrow & (N_ - 1);
        int h = jcol >> 6, dh = jcol & (DH_ - 1);
        half4 o;
#pragma unroll
        for (int r = 0; r < 4; ++r) o[r] = (_Float16)acc[mt][nt][r];
        *(half4*)(VtG + ((size_t)((b * H_ + h) * DH_ + dh)) * N_ + key) = o;
      } else {
#pragma unroll
        for (int r = 0; r < 4; ++r) {
          float val = acc[mt][nt][r];
          int m = mrow + r;
          if (MODE == 0) {
            int b = m >> 11, n = m & (N_ - 1);
            int h = jcol >> 6, dh = jcol & (DH_ - 1);
            Chead[((((size_t)(b * H_ + h)) * N_ + n) * DH_) + dh] = (_Float16)val;
          } else {
            Cf32[(size_t)m * D_ + jcol] = val;
          }
        }
      }
    }
  }
}

// ---------------------------------------------------------------------------
// Flash attention, NO LDS / NO BARRIERS. Each wave independently handles
// (head, 32 q-rows); K/V fragments loaded directly from global (full-line
// utilization: one K row = one 128B line; VtG 64-key spans are 128B-aligned).
// S^T = K·Q^T, no-max softmax, l via ones-MFMA. 512 blocks x 4 waves.
__global__ __launch_bounds__(256) void attn_kernel(
    const _Float16* __restrict__ Qh, const _Float16* __restrict__ Kh,
    const _Float16* __restrict__ VtG, const int* __restrict__ vlen,
    _Float16* __restrict__ Hd, const int* __restrict__ order) {
  const int tid = threadIdx.x, lane = tid & 63, w = tid >> 6;
  const int quad = lane >> 4, l15 = lane & 15;
  const int gid = blockIdx.x * 4 + w;   // 0..2047 wave-items
  const int bh = order[gid >> 6];
  const int q0 = (gid & 63) * 32;
  const int b = bh >> 4, h = bh & (H_ - 1);
  const int vl = vlen[bh];
  const int KT = (vl + 63) >> 6;
  const float sc2 = 0.125f * 1.44269504088896f;  // (1/sqrt(64))*log2(e)
  const half4 ones = {(_Float16)1, (_Float16)1, (_Float16)1, (_Float16)1};

  const _Float16* Qb = Qh  + (size_t)bh * N_ * DH_;
  const _Float16* Kb = Kh  + (size_t)bh * N_ * DH_;
  const _Float16* Vb = VtG + (size_t)bh * N_ * DH_;  // [dh][key=N]

  // Q fragments: 2 groups of 16 q, each 2 K-halves
  half8 qb[2][2];
#pragma unroll
  for (int qh = 0; qh < 2; ++qh)
#pragma unroll
    for (int kk = 0; kk < 2; ++kk)
      qb[qh][kk] = *(const half8*)(Qb + (size_t)(q0 + qh * 16 + l15) * DH_ +
                                   kk * 32 + quad * 8);

  f32x4 Oacc[4][2] = {};
  f32x4 lacc[2] = {};

  for (int kt = 0; kt < KT; ++kt) {
    const int k0 = kt * 64;
    // K fragments: rows nt*16+l15 (one 128B line each), cols quad*8 (+32)
    half8 ka[4][2];
#pragma unroll
    for (int nt = 0; nt < 4; ++nt)
#pragma unroll
      for (int kk = 0; kk < 2; ++kk)
        ka[nt][kk] = *(const half8*)(Kb + (size_t)(k0 + nt * 16 + l15) * DH_ +
                                     kk * 32 + quad * 8);
    // V fragments: va[dt][nt] = Vt[dh=dt*16+l15][k0 + (nt*4+quad)*4 ..+4]
    half4 va[4][4];
#pragma unroll
    for (int dt = 0; dt < 4; ++dt)
#pragma unroll
      for (int nt = 0; nt < 4; ++nt)
        va[dt][nt] = *(const half4*)(Vb + (size_t)(dt * 16 + l15) * N_ + k0 +
                                     (nt * 4 + quad) * 4);

    // S^T = K·Q^T for both q-groups
    f32x4 s[4][2];
#pragma unroll
    for (int nt = 0; nt < 4; ++nt)
#pragma unroll
      for (int qh = 0; qh < 2; ++qh) {
        f32x4 c = {};
        c = __builtin_amdgcn_mfma_f32_16x16x32_f16(ka[nt][0], qb[qh][0], c, 0, 0, 0);
        c = __builtin_amdgcn_mfma_f32_16x16x32_f16(ka[nt][1], qb[qh][1], c, 0, 0, 0);
        s[nt][qh] = c;
      }
    // no-max softmax
    half4 pf[4][2];
    if (k0 + 64 <= vl) {
#pragma unroll
      for (int nt = 0; nt < 4; ++nt)
#pragma unroll
        for (int qh = 0; qh < 2; ++qh)
#pragma unroll
          for (int r = 0; r < 4; ++r)
            pf[nt][qh][r] = (_Float16)exp2f(s[nt][qh][r] * sc2);
    } else {
#pragma unroll
      for (int nt = 0; nt < 4; ++nt) {
        int keyb = k0 + nt * 16 + quad * 4;
#pragma unroll
        for (int qh = 0; qh < 2; ++qh)
#pragma unroll
          for (int r = 0; r < 4; ++r) {
            float p = exp2f(s[nt][qh][r] * sc2);
            pf[nt][qh][r] = (keyb + r < vl) ? (_Float16)p : (_Float16)0.f;
          }
      }
    }
    // O^T += V^T·P^T ; l += ones·P^T
#pragma unroll
    for (int nt = 0; nt < 4; ++nt)
#pragma unroll
      for (int qh = 0; qh < 2; ++qh) {
        lacc[qh] = __builtin_amdgcn_mfma_f32_16x16x16f16(ones, pf[nt][qh],
                                                         lacc[qh], 0, 0, 0);
#pragma unroll
        for (int dt = 0; dt < 4; ++dt)
          Oacc[dt][qh] = __builtin_amdgcn_mfma_f32_16x16x16f16(
              va[dt][nt], pf[nt][qh], Oacc[dt][qh], 0, 0, 0);
      }
  }

  // epilogue
#pragma unroll
  for (int qh = 0; qh < 2; ++qh) {
    float inv_l = 1.0f / lacc[qh][0];
    int q = q0 + qh * 16 + l15;
    _Float16* out = Hd + ((size_t)(b * N_ + q)) * D_ + h * DH_;
#pragma unroll
    for (int dt = 0; dt < 4; ++dt) {
      half4 o;
#pragma unroll
      for (int r = 0; r < 4; ++r) o[r] = (_Float16)(Oacc[dt][qh][r] * inv_l);
      *(half4*)(out + dt * 16 + quad * 4) = o;
    }
  }
}

// ---------------------------------------------------------------------------
extern "C" void kernel_launch(void* const* d_in, const int* in_sizes, int n_in,
                              void* d_out, int out_size, void* d_ws, size_t ws_size,
                              hipStream_t stream) {
  const float* q  = (const float*)d_in[0];
  const float* k  = (const float*)d_in[1];
  const float* v  = (const float*)d_in[2];
  const int*   vl = (const int*)d_in[3];
  const float* Wq = (const float*)d_in[4];
  const float* Wk = (const float*)d_in[5];
  const float* Wv = (const float*)d_in[6];
  const float* Wo = (const float*)d_in[7];

  const size_t XSZ = (size_t)B_ * N_ * D_;  // 4M elements
  const size_t WSZ = (size_t)D_ * D_;       // 1M elements
  _Float16* ws = (_Float16*)d_ws;
  _Float16* Xf  = ws;                // 3*XSZ fp16 q,k,v inputs
  _Float16* Wt  = Xf + 3 * XSZ;      // 4*WSZ fp16 W^T x4
  _Float16* Qh  = Wt + 4 * WSZ;      // XSZ (Q head-split)
  _Float16* Kh  = Qh + XSZ;          // XSZ (K head-split)
  _Float16* VtG = Kh + XSZ;          // XSZ (V transposed [bh][dh][key])
  _Float16* Hd  = VtG + XSZ;         // XSZ (attn out, merged heads)
  int* order = (int*)(Hd + XSZ);     // 32-entry LPT head order

  prep_kernel<<<dim3(6144 + 1024 + 1), 256, 0, stream>>>(
      q, k, v, Wq, Wk, Wv, Wo, vl, Xf, Wt, order);

  // fused Q/K/V projections; z=2 writes transposed V directly
  gemm_f16_kernel<4, 0><<<dim3(D_ / 128, 32, 3), 256, 0, stream>>>(
      Xf, Wt, Qh, VtG, nullptr);

  attn_kernel<<<dim3(512), 256, 0, stream>>>(Qh, Kh, VtG, vl, Hd, order);

  // output projection (BN=64 -> 512 blocks)
  gemm_f16_kernel<2, 1><<<dim3(D_ / 64, 32, 1), 256, 0, stream>>>(
      Hd, Wt + 3 * WSZ, nullptr, nullptr, (float*)d_out);
}